// Round 8
// baseline (134.299 us; speedup 1.0000x reference)
//
#include <hip/hip_runtime.h>
#include <math.h>

#define N_ 4
#define C_ 64
#define H_ 128
#define W_ 128
#define HW_ (H_ * W_)
#define K2_ 9
#define COUT 64
#define CK 576          // K = 9 taps * 64 channels, order k*64+c
#define TP 16           // pixels per tile
#define NT 2            // tiles per block-iteration
#define SST 584         // s_x row stride (elems)
#define GUARD 128       // guard elems (256 B) before/after xT for unclamped-x loads
#define DEPTH 6         // gather pipeline: groups in flight
#define SLOTS 7         // buf slots (issue-before-consume needs DEPTH+1)

typedef __bf16 bf16x8 __attribute__((ext_vector_type(8)));
typedef __bf16 bf16x2 __attribute__((ext_vector_type(2)));
typedef float floatx4 __attribute__((ext_vector_type(4)));
typedef float floatx2 __attribute__((ext_vector_type(2)));
typedef unsigned uint2v __attribute__((ext_vector_type(2)));
typedef unsigned uint4v __attribute__((ext_vector_type(4)));

__device__ __forceinline__ float bflo(unsigned u) {
    return __builtin_bit_cast(float, u << 16);
}
__device__ __forceinline__ float bfhi(unsigned u) {
    return __builtin_bit_cast(float, u & 0xffff0000u);
}

// ---- prep: (a) NCHW fp32 -> NHWC bf16 transpose, (b) weight re-layout ----
__global__ __launch_bounds__(256) void prep_kernel(const float* __restrict__ x,
                                                   const float* __restrict__ w,
                                                   const float* __restrict__ w_off,
                                                   __bf16* __restrict__ xT,
                                                   __bf16* __restrict__ w2,
                                                   __bf16* __restrict__ w_off2) {
    __shared__ float s_t[64][33];
    int t = threadIdx.x;
    int bx = blockIdx.x;
    int y = blockIdx.y, n = blockIdx.z;
    if (bx < 4) {
        int x0 = bx * 32;
        int c = t >> 2, seg = (t & 3) * 8;
        const float* src = x + (((size_t)n * C_ + c) * H_ + y) * W_ + x0 + seg;
        floatx4 v0 = *(const floatx4*)src;
        floatx4 v1 = *(const floatx4*)(src + 4);
#pragma unroll
        for (int j = 0; j < 4; ++j) { s_t[c][seg + j] = v0[j]; s_t[c][seg + 4 + j] = v1[j]; }
        __syncthreads();
        int xl = t >> 3, cb = (t & 7) * 8;
        bf16x8 o;
#pragma unroll
        for (int j = 0; j < 8; ++j) o[j] = (__bf16)s_t[cb + j][xl];
        *(bf16x8*)(xT + (((size_t)n * H_ + y) * W_ + x0 + xl) * C_ + cb) = o;
    } else {
        int linear = (n * 128 + y) * 256 + t;
        if (linear < COUT * CK) {
            int o = linear / CK, r = linear - o * CK;
            int k = r >> 6, c = r & 63;
            w2[linear] = (__bf16)w[(o * C_ + c) * K2_ + k];
        }
        if (linear < 32 * CK) {
            int o = linear / CK, r = linear - o * CK;
            int k = r >> 6, c = r & 63;
            w_off2[linear] = (o < 27) ? (__bf16)w_off[(o * C_ + c) * K2_ + k] : (__bf16)0.f;
        }
    }
}

// Persistent-row blocks: 512 blocks (2/CU resident), each owns one image row
// (n, ho) and loops over its four 32-pixel tile-pairs. Phase-D weights dw[18]
// (72 VGPR) are asm-loaded ONCE before the loop (retired by tile-0's Phase-A
// vmcnt, FIFO); tiles 1-3 have zero Phase-D weight chains (the cost R6 proved
// at ~20us/doubling). Phase-B weights per-tile, hidden under A's batch. XCD
// swizzle groups 64 consecutive rows per XCD L2 for im2col row reuse.
__global__ __launch_bounds__(256, 2) void fused_kernel(const __bf16* __restrict__ xT,
                                                       const __bf16* __restrict__ w2,
                                                       const __bf16* __restrict__ w_off2,
                                                       const float* __restrict__ b_off,
                                                       const float* __restrict__ b,
                                                       float* __restrict__ out) {
    __shared__ __align__(16) __bf16 s_x[NT][TP * SST];  // sampled B^T tiles [p][k*64+c]
    __shared__ float s_om[NT][2][32 * TP];              // offset-conv K-half partials
    __shared__ floatx4 s_w4[NT][K2_ * TP];              // position weights (mask folded)
    __shared__ int s_pix[NT][K2_ * TP];                 // clamped base pixel index

    int t = threadIdx.x;
    // bijective XCD swizzle (512 % 8 == 0): XCD k gets rows 64k..64k+63
    int bid = ((int)blockIdx.x & 7) * 64 + ((int)blockIdx.x >> 3);
    int ho = bid & (H_ - 1);
    int n  = bid >> 7;
    const __bf16* xn = xT + (size_t)n * HW_ * C_;

    int lane = t & 63;
    int wv   = t >> 6;
    int half = lane >> 5;
    int li   = lane & 31;
    int q    = lane >> 4;
    int col  = lane & 15;

    // ---- persistent Phase-D weight preload (once; retired by tile-0 Phase-A wait) ----
    uint4v dw[18];
    {
        const __bf16* wp0 = w2 + (size_t)(16 * wv + col) * CK + q * 8;
#pragma unroll
        for (int it = 0; it < 18; ++it) {
            asm volatile("global_load_dwordx4 %0, %1, off"
                         : "=&v"(dw[it]) : "v"(wp0 + 32 * it));
        }
    }

#pragma unroll 1
    for (int jj = 0; jj < 4; ++jj) {
        int wo0 = 32 * jj;
        uint4v wb[9];                                   // Phase-B weight fragments

        // ---- Phase A: im2col asm batch (18 dwordx2) + Phase-B weight issue ----
        {
            uint2v ua[18];
            int tl = wv >> 1;                           // wave-uniform tile
            int rb = (wv & 1) * 36 + half;              // pair index base within tile
#pragma unroll
            for (int j = 0; j < 18; ++j) {
                int r  = rb + 2 * j;                    // 0..71: k = r>>3, pj = r&7
                int k  = r >> 3;
                int p0 = (r & 7) * 2;
                int kh = k / 3, kw = k - kh * 3;
                int y  = ho - 1 + kh;
                int yc = min(max(y, 0), H_ - 1);
                int xx = wo0 + 16 * tl + p0 - 1 + kw;   // unclamped (pair: xx, xx+1)
                int pix = yc * W_ + xx;                 // guard makes -1/OOB reads safe
                const __bf16* ap = xn + (ptrdiff_t)pix * C_ + 4 * li;
                asm volatile("global_load_dwordx2 %0, %1, off"
                             : "=&v"(ua[j]) : "v"(ap));
            }
            {
                int r = wv >> 1, h = wv & 1;
                const __bf16* wp0 = w_off2 + (size_t)(16 * r + col) * CK + h * 288 + q * 8;
#pragma unroll
                for (int it = 0; it < 9; ++it) {
                    asm volatile("global_load_dwordx4 %0, %1, off"
                                 : "=&v"(wb[it]) : "v"(wp0 + 32 * it));
                }
            }
            // barrier BEFORE the LDS writes: protects prev tile's Phase-D s_x reads;
            // overlaps with the in-flight loads. jj=0: harmless.
            __syncthreads();
            // FIFO: retires [prev stores +] dw (jj=0) + ua; leaves wb's 9 in flight
            asm volatile("s_waitcnt vmcnt(9)" ::: "memory");
            __builtin_amdgcn_sched_barrier(0);
#pragma unroll
            for (int j = 0; j < 18; ++j) {
                int r  = rb + 2 * j;
                int k  = r >> 3;
                int p0 = (r & 7) * 2;
                int kh = k / 3, kw = k - kh * 3;
                int y  = ho - 1 + kh;
                int xx = wo0 + 16 * tl + p0 - 1 + kw;
                bool vy = (unsigned)y < (unsigned)H_;
                // lanes 0..15 hold pixel p0 (tap xx), lanes 16..31 hold p0+1 (tap xx+1)
                int myxx = xx + (li >> 4);
                bool valid = vy && ((unsigned)myxx < (unsigned)W_);
                uint2v v = ua[j];
                v.x = valid ? v.x : 0u;
                v.y = valid ? v.y : 0u;
                int p = p0 + (li >> 4);
                *(uint2v*)&s_x[tl][p * SST + k * 64 + 4 * (li & 15)] = v;
            }
        }
        __syncthreads();

        // ---- Phase B: offset conv from REGISTER A-fragments; B from LDS; A shared ----
        {
            int r = wv >> 1;
            int h = wv & 1;
            asm volatile("s_waitcnt vmcnt(0)" ::: "memory"); // wb ready
            __builtin_amdgcn_sched_barrier(0);
            const __bf16* b0 = s_x[0] + col * SST + h * 288 + q * 8;
            const __bf16* b1 = s_x[1] + col * SST + h * 288 + q * 8;
            floatx4 acc0 = {0.f, 0.f, 0.f, 0.f}, acc1 = {0.f, 0.f, 0.f, 0.f};
#pragma unroll
            for (int it = 0; it < 9; ++it) {
                bf16x8 a   = __builtin_bit_cast(bf16x8, wb[it]);
                bf16x8 bb0 = *(const bf16x8*)(b0 + 32 * it);
                bf16x8 bb1 = *(const bf16x8*)(b1 + 32 * it);
                acc0 = __builtin_amdgcn_mfma_f32_16x16x32_bf16(a, bb0, acc0, 0, 0, 0);
                acc1 = __builtin_amdgcn_mfma_f32_16x16x32_bf16(a, bb1, acc1, 0, 0, 0);
            }
#pragma unroll
            for (int rr = 0; rr < 4; ++rr) {
                s_om[0][h][(16 * r + q * 4 + rr) * TP + col] = acc0[rr];
                s_om[1][h][(16 * r + q * 4 + rr) * TP + col] = acc1[rr];
            }
        }
        __syncthreads();

        // ---- coords: position-weights + clamped base pixel (288 items, 2 passes) ----
#pragma unroll
        for (int it2 = 0; it2 < 2; ++it2) {
            int i = it2 * 256 + t;
            if (i < NT * K2_ * TP) {
                int tl = (i >= 144);
                int P  = i - 144 * tl;
                int k  = P >> 4;
                int pp = P & 15;
                float dy = s_om[tl][0][(2 * k) * TP + pp]     + s_om[tl][1][(2 * k) * TP + pp]     + b_off[2 * k];
                float dx = s_om[tl][0][(2 * k + 1) * TP + pp] + s_om[tl][1][(2 * k + 1) * TP + pp] + b_off[2 * k + 1];
                float mm = s_om[tl][0][(18 + k) * TP + pp]    + s_om[tl][1][(18 + k) * TP + pp]    + b_off[18 + k];
                float msk = 1.f / (1.f + expf(-mm));
                int kh = k / 3, kw = k - kh * 3;
                float py = (float)(ho - 1 + kh) + dy;
                float px = (float)(wo0 + 16 * tl + pp - 1 + kw) + dx;
                float yf = floorf(py), xf = floorf(px);
                float fy = py - yf, fx = px - xf;
                int y0 = (int)yf, x0 = (int)xf;
                float wy0 = ((unsigned)y0 < (unsigned)H_)       ? 1.f - fy : 0.f;
                float wy1 = ((unsigned)(y0 + 1) < (unsigned)H_) ? fy       : 0.f;
                float wx0 = ((unsigned)x0 < (unsigned)W_)       ? 1.f - fx : 0.f;
                float wx1 = ((unsigned)(x0 + 1) < (unsigned)W_) ? fx      : 0.f;
                int y0c = min(max(y0, 0), H_ - 2);
                int x0c = min(max(x0, 0), W_ - 2);
                // shift weights onto clamped positions (OOB-safe addresses, exact zeros)
                float t0 = (y0 == y0c) ? wy0 : ((y0 + 1 == y0c) ? wy1 : 0.f);
                float t1 = (y0 == y0c) ? wy1 : ((y0 == y0c + 1) ? wy0 : 0.f);
                float u0 = (x0 == x0c) ? wx0 : ((x0 + 1 == x0c) ? wx1 : 0.f);
                float u1 = (x0 == x0c) ? wx1 : ((x0 == x0c + 1) ? wx0 : 0.f);
                floatx4 w4 = { t0 * u0 * msk, t0 * u1 * msk, t1 * u0 * msk, t1 * u1 * msk };
                s_w4[tl][P] = w4;
                s_pix[tl][P] = y0c * W_ + x0c;
            }
        }
        __syncthreads();

        // ---- Phase C: bilinear gather; half-wave per (k,p); asm depth-6 pipeline ----
        {
            int Pb = wv * 36 + half;
            unsigned buf[SLOTS][4];

#define ISSUE(gi)                                                                  \
            do {                                                                   \
                int tl_ = ((gi) >= 18);                                            \
                int pix = s_pix[tl_][Pb + 2 * ((gi) - 18 * tl_)];                  \
                const __bf16* a0 = xn + (ptrdiff_t)pix * C_ + 2 * li;              \
                const __bf16* a1 = a0 + W_ * C_;                                   \
                asm volatile("global_load_dword %0, %4, off\n\t"                   \
                             "global_load_dword %1, %4, off offset:128\n\t"        \
                             "global_load_dword %2, %5, off\n\t"                   \
                             "global_load_dword %3, %5, off offset:128"            \
                             : "=&v"(buf[(gi) % SLOTS][0]), "=&v"(buf[(gi) % SLOTS][1]), \
                               "=&v"(buf[(gi) % SLOTS][2]), "=&v"(buf[(gi) % SLOTS][3])  \
                             : "v"(a0), "v"(a1));                                  \
            } while (0)

#define STEP(g, NW)                                                                \
            do {                                                                   \
                if ((g) + DEPTH < 36) ISSUE((g) + DEPTH);                          \
                int tl_ = ((g) >= 18);                                             \
                int P_  = Pb + 2 * ((g) - 18 * tl_);                               \
                floatx4 w4_ = s_w4[tl_][P_];                                       \
                asm volatile("s_waitcnt vmcnt(" #NW ")" ::: "memory");             \
                __builtin_amdgcn_sched_barrier(0);                                 \
                float lo = w4_[0] * bflo(buf[(g) % SLOTS][0])                      \
                         + w4_[1] * bflo(buf[(g) % SLOTS][1])                      \
                         + w4_[2] * bflo(buf[(g) % SLOTS][2])                      \
                         + w4_[3] * bflo(buf[(g) % SLOTS][3]);                     \
                float hi = w4_[0] * bfhi(buf[(g) % SLOTS][0])                      \
                         + w4_[1] * bfhi(buf[(g) % SLOTS][1])                      \
                         + w4_[2] * bfhi(buf[(g) % SLOTS][2])                      \
                         + w4_[3] * bfhi(buf[(g) % SLOTS][3]);                     \
                floatx2 fv = {lo, hi};                                             \
                bf16x2 bv = __builtin_convertvector(fv, bf16x2);                   \
                int k_ = P_ >> 4, p_ = P_ & 15;                                    \
                *(unsigned*)&s_x[tl_][p_ * SST + k_ * 64 + 2 * li] =               \
                    __builtin_bit_cast(unsigned, bv);                              \
            } while (0)

            ISSUE(0); ISSUE(1); ISSUE(2); ISSUE(3); ISSUE(4); ISSUE(5);
            STEP(0, 24);  STEP(1, 24);  STEP(2, 24);  STEP(3, 24);  STEP(4, 24);
            STEP(5, 24);  STEP(6, 24);  STEP(7, 24);  STEP(8, 24);  STEP(9, 24);
            STEP(10, 24); STEP(11, 24); STEP(12, 24); STEP(13, 24); STEP(14, 24);
            STEP(15, 24); STEP(16, 24); STEP(17, 24); STEP(18, 24); STEP(19, 24);
            STEP(20, 24); STEP(21, 24); STEP(22, 24); STEP(23, 24); STEP(24, 24);
            STEP(25, 24); STEP(26, 24); STEP(27, 24); STEP(28, 24); STEP(29, 24);
            STEP(30, 20); STEP(31, 16); STEP(32, 12); STEP(33, 8);  STEP(34, 4);
            STEP(35, 0);
#undef STEP
#undef ISSUE
        }
        __syncthreads();

        // ---- Phase D: main conv MFMA from PERSISTENT register A-fragments ----
        {
            const __bf16* b0 = s_x[0] + col * SST + q * 8;
            const __bf16* b1 = s_x[1] + col * SST + q * 8;
            floatx4 acc0 = {0.f, 0.f, 0.f, 0.f}, acc1 = {0.f, 0.f, 0.f, 0.f};
#pragma unroll
            for (int it = 0; it < 18; ++it) {
                bf16x8 a   = __builtin_bit_cast(bf16x8, dw[it]);
                bf16x8 bb0 = *(const bf16x8*)(b0 + 32 * it);
                bf16x8 bb1 = *(const bf16x8*)(b1 + 32 * it);
                acc0 = __builtin_amdgcn_mfma_f32_16x16x32_bf16(a, bb0, acc0, 0, 0, 0);
                acc1 = __builtin_amdgcn_mfma_f32_16x16x32_bf16(a, bb1, acc1, 0, 0, 0);
            }
#pragma unroll
            for (int r = 0; r < 4; ++r) {
                int o = 16 * wv + q * 4 + r;
                float bias = b[o];
                float* ob = out + (((size_t)n * COUT + o) * H_ + ho) * W_ + wo0;
                ob[col]      = fmaxf(acc0[r] + bias, 0.f);
                ob[16 + col] = fmaxf(acc1[r] + bias, 0.f);
            }
        }
    }
}

extern "C" void kernel_launch(void* const* d_in, const int* in_sizes, int n_in,
                              void* d_out, int out_size, void* d_ws, size_t ws_size,
                              hipStream_t stream) {
    const float* x     = (const float*)d_in[0];
    const float* w_off = (const float*)d_in[1];
    const float* b_off = (const float*)d_in[2];
    const float* w     = (const float*)d_in[3];
    const float* b     = (const float*)d_in[4];
    float* out = (float*)d_out;

    // workspace: [256B guard][xT NHWC bf16 8.39MB][256B guard][w2][w_off2]
    __bf16* xT     = (__bf16*)d_ws + GUARD;
    __bf16* w2     = xT + (size_t)N_ * HW_ * C_ + GUARD;
    __bf16* w_off2 = w2 + (size_t)COUT * CK;

    prep_kernel<<<dim3(5, 128, 4), 256, 0, stream>>>(x, w, w_off, xT, w2, w_off2);

    fused_kernel<<<512, 256, 0, stream>>>(xT, w2, w_off2, b_off, b, out);
}

// Round 9
// 122.383 us; speedup vs baseline: 1.0974x; 1.0974x over previous
//
#include <hip/hip_runtime.h>
#include <math.h>

#define N_ 4
#define C_ 64
#define H_ 128
#define W_ 128
#define HW_ (H_ * W_)
#define K2_ 9
#define COUT 64
#define CK 576          // K = 9 taps * 64 channels, order k*64+c
#define TP 16           // pixels per tile
#define NT 2            // tiles per block
#define SST 584         // s_x row stride (elems)
#define GUARD 128       // guard elems (256 B) before/after xT for unclamped-x loads
#define DEPTH 6         // gather pipeline: groups in flight
#define SLOTS 7         // buf slots (issue-before-consume needs DEPTH+1)
#define PXS 68          // row-buffer px stride (elems): 64 data + 4 pad (bank spread)
#define RS  (34 * PXS)  // row-buffer row stride (34 px window)

typedef __bf16 bf16x8 __attribute__((ext_vector_type(8)));
typedef __bf16 bf16x2 __attribute__((ext_vector_type(2)));
typedef float floatx4 __attribute__((ext_vector_type(4)));
typedef float floatx2 __attribute__((ext_vector_type(2)));
typedef unsigned uint2v __attribute__((ext_vector_type(2)));
typedef unsigned uint4v __attribute__((ext_vector_type(4)));

__device__ __forceinline__ float bflo(unsigned u) {
    return __builtin_bit_cast(float, u << 16);
}
__device__ __forceinline__ float bfhi(unsigned u) {
    return __builtin_bit_cast(float, u & 0xffff0000u);
}

// ---- prep: (a) NCHW fp32 -> NHWC bf16 transpose, (b) weight re-layout ----
__global__ __launch_bounds__(256) void prep_kernel(const float* __restrict__ x,
                                                   const float* __restrict__ w,
                                                   const float* __restrict__ w_off,
                                                   __bf16* __restrict__ xT,
                                                   __bf16* __restrict__ w2,
                                                   __bf16* __restrict__ w_off2) {
    __shared__ float s_t[64][33];
    int t = threadIdx.x;
    int bx = blockIdx.x;
    int y = blockIdx.y, n = blockIdx.z;
    if (bx < 4) {
        int x0 = bx * 32;
        int c = t >> 2, seg = (t & 3) * 8;
        const float* src = x + (((size_t)n * C_ + c) * H_ + y) * W_ + x0 + seg;
        floatx4 v0 = *(const floatx4*)src;
        floatx4 v1 = *(const floatx4*)(src + 4);
#pragma unroll
        for (int j = 0; j < 4; ++j) { s_t[c][seg + j] = v0[j]; s_t[c][seg + 4 + j] = v1[j]; }
        __syncthreads();
        int xl = t >> 3, cb = (t & 7) * 8;
        bf16x8 o;
#pragma unroll
        for (int j = 0; j < 8; ++j) o[j] = (__bf16)s_t[cb + j][xl];
        *(bf16x8*)(xT + (((size_t)n * H_ + y) * W_ + x0 + xl) * C_ + cb) = o;
    } else {
        int linear = (n * 128 + y) * 256 + t;
        if (linear < COUT * CK) {
            int o = linear / CK, r = linear - o * CK;
            int k = r >> 6, c = r & 63;
            w2[linear] = (__bf16)w[(o * C_ + c) * K2_ + k];
        }
        if (linear < 32 * CK) {
            int o = linear / CK, r = linear - o * CK;
            int k = r >> 6, c = r & 63;
            w_off2[linear] = (o < 27) ? (__bf16)w_off[(o * C_ + c) * K2_ + k] : (__bf16)0.f;
        }
    }
}

// R0/R4 proven structure with Phase A's im2col REMOVED: the offset-conv B-operand
// is read directly from an un-duplicated 3-row window buffer (3 x 34px x 64ch,
// 13KB vs 36.9KB staged) with compile-time immediate offsets per MFMA iteration
// (kh*RS + kw*PXS + chalf*32, h branched so all fold). Phase A: 18 guarded loads
// + ~200 addr-VALU per wave -> 4 dwordx4 loads/thread. Row buffer unions into
// s_x[0] (dead until Phase C, 2 barriers after its last read). C/D identical to
// the verified R4 asm pipeline.
__global__ __launch_bounds__(256) void fused_kernel(const __bf16* __restrict__ xT,
                                                    const __bf16* __restrict__ w2,
                                                    const __bf16* __restrict__ w_off2,
                                                    const float* __restrict__ b_off,
                                                    const float* __restrict__ b,
                                                    float* __restrict__ out) {
    __shared__ __align__(16) __bf16 s_x[NT][TP * SST];  // sampled B^T tiles [p][k*64+c]
    __shared__ float s_om[NT][2][32 * TP];              // offset-conv K-half partials
    __shared__ floatx4 s_w4[NT][K2_ * TP];              // position weights (mask folded)
    __shared__ int s_pix[NT][K2_ * TP];                 // clamped base pixel index
    __bf16* s_row = &s_x[0][0];                         // 3-row window (13.9KB, dies at C)

    int t = threadIdx.x;
    int pixbase = blockIdx.x * (TP * NT);               // over N*H*W, 32 px/block
    int wo0 = pixbase & (W_ - 1);                       // 0,32,64,96 (never crosses row)
    int ho  = (pixbase >> 7) & (H_ - 1);
    int n   = pixbase >> 14;
    const __bf16* xn = xT + (size_t)n * HW_ * C_;

    int lane = t & 63;
    int wv   = t >> 6;
    int half = lane >> 5;
    int li   = lane & 31;
    int q    = lane >> 4;
    int col  = lane & 15;

    // ---- Phase A: stage 3 input rows (y=ho-1..ho+1, x=wo0-1..wo0+32), zeroed OOB ----
    {
        uint4v va[4];
#pragma unroll
        for (int it = 0; it < 4; ++it) {
            int i  = it * 256 + t;                      // chunk id; 816 = 3*34*8 active
            int s  = i & 7;                             // 16B chunk within 64ch
            int pr = i >> 3;
            int r  = pr / 34;                           // window row 0..2 (3 = inactive)
            int p  = pr - r * 34;                       // window px 0..33
            int y  = ho - 1 + r;
            int yc = min(max(y, 0), H_ - 1);
            int x  = wo0 - 1 + p;                       // -1..128: guard makes reads safe
            const __bf16* ap = xn + (ptrdiff_t)(yc * W_ + x) * C_ + s * 8;
            va[it] = *(const uint4v*)ap;
        }
#pragma unroll
        for (int it = 0; it < 4; ++it) {
            int i  = it * 256 + t;
            int s  = i & 7;
            int pr = i >> 3;
            int r  = pr / 34;
            int p  = pr - r * 34;
            int y  = ho - 1 + r;
            int x  = wo0 - 1 + p;
            bool valid = ((unsigned)y < (unsigned)H_) && ((unsigned)x < (unsigned)W_);
            uint4v v = va[it];
            if (!valid) v = (uint4v){0u, 0u, 0u, 0u};
            if (i < 3 * 34 * 8) *(uint4v*)&s_row[r * RS + p * PXS + s * 8] = v;
        }
    }
    __syncthreads();

    // ---- Phase B: offset conv; B-fragments from the row window, imm offsets ----
    {
        int r = wv >> 1;
        int h = wv & 1;
        const __bf16* ar  = w_off2 + (size_t)(16 * r + col) * CK + h * 288 + q * 8;
        const __bf16* rb0 = s_row + col * PXS + q * 8;
        const __bf16* rb1 = rb0 + 16 * PXS;
        floatx4 acc0 = {0.f, 0.f, 0.f, 0.f}, acc1 = {0.f, 0.f, 0.f, 0.f};
#define BSTEP(j, KBASE)                                                              \
        {                                                                            \
            const int K_  = (KBASE) + (j) * 32;                                      \
            const int kk  = K_ >> 6;                                                 \
            const int ch  = (K_ >> 5) & 1;                                           \
            const int kh  = kk / 3, kw = kk - kh * 3;                                \
            const int off = kh * RS + kw * PXS + ch * 32;                            \
            bf16x8 a  = *(const bf16x8*)(ar + 32 * (j));                             \
            bf16x8 b0 = *(const bf16x8*)(rb0 + off);                                 \
            bf16x8 b1 = *(const bf16x8*)(rb1 + off);                                 \
            acc0 = __builtin_amdgcn_mfma_f32_16x16x32_bf16(a, b0, acc0, 0, 0, 0);    \
            acc1 = __builtin_amdgcn_mfma_f32_16x16x32_bf16(a, b1, acc1, 0, 0, 0);    \
        }
        if (h == 0) {
            BSTEP(0, 0) BSTEP(1, 0) BSTEP(2, 0) BSTEP(3, 0) BSTEP(4, 0)
            BSTEP(5, 0) BSTEP(6, 0) BSTEP(7, 0) BSTEP(8, 0)
        } else {
            BSTEP(0, 288) BSTEP(1, 288) BSTEP(2, 288) BSTEP(3, 288) BSTEP(4, 288)
            BSTEP(5, 288) BSTEP(6, 288) BSTEP(7, 288) BSTEP(8, 288)
        }
#undef BSTEP
#pragma unroll
        for (int rr = 0; rr < 4; ++rr) {
            s_om[0][h][(16 * r + q * 4 + rr) * TP + col] = acc0[rr];
            s_om[1][h][(16 * r + q * 4 + rr) * TP + col] = acc1[rr];
        }
    }
    __syncthreads();

    // ---- coords: position-weights + clamped base pixel (288 items, 2 passes) ----
#pragma unroll
    for (int it2 = 0; it2 < 2; ++it2) {
        int i = it2 * 256 + t;
        if (i < NT * K2_ * TP) {
            int tl = (i >= 144);
            int P  = i - 144 * tl;
            int k  = P >> 4;
            int pp = P & 15;
            float dy = s_om[tl][0][(2 * k) * TP + pp]     + s_om[tl][1][(2 * k) * TP + pp]     + b_off[2 * k];
            float dx = s_om[tl][0][(2 * k + 1) * TP + pp] + s_om[tl][1][(2 * k + 1) * TP + pp] + b_off[2 * k + 1];
            float mm = s_om[tl][0][(18 + k) * TP + pp]    + s_om[tl][1][(18 + k) * TP + pp]    + b_off[18 + k];
            float msk = 1.f / (1.f + expf(-mm));
            int kh = k / 3, kw = k - kh * 3;
            float py = (float)(ho - 1 + kh) + dy;
            float px = (float)(wo0 + 16 * tl + pp - 1 + kw) + dx;
            float yf = floorf(py), xf = floorf(px);
            float fy = py - yf, fx = px - xf;
            int y0 = (int)yf, x0 = (int)xf;
            float wy0 = ((unsigned)y0 < (unsigned)H_)       ? 1.f - fy : 0.f;
            float wy1 = ((unsigned)(y0 + 1) < (unsigned)H_) ? fy       : 0.f;
            float wx0 = ((unsigned)x0 < (unsigned)W_)       ? 1.f - fx : 0.f;
            float wx1 = ((unsigned)(x0 + 1) < (unsigned)W_) ? fx      : 0.f;
            int y0c = min(max(y0, 0), H_ - 2);
            int x0c = min(max(x0, 0), W_ - 2);
            // shift weights onto clamped positions (OOB-safe addresses, exact zeros)
            float t0 = (y0 == y0c) ? wy0 : ((y0 + 1 == y0c) ? wy1 : 0.f);
            float t1 = (y0 == y0c) ? wy1 : ((y0 == y0c + 1) ? wy0 : 0.f);
            float u0 = (x0 == x0c) ? wx0 : ((x0 + 1 == x0c) ? wx1 : 0.f);
            float u1 = (x0 == x0c) ? wx1 : ((x0 == x0c + 1) ? wx0 : 0.f);
            floatx4 w4 = { t0 * u0 * msk, t0 * u1 * msk, t1 * u0 * msk, t1 * u1 * msk };
            s_w4[tl][P] = w4;
            s_pix[tl][P] = y0c * W_ + x0c;
        }
    }
    __syncthreads();

    // ---- Phase C: bilinear sample; half-wave per (k,p); 36 groups, asm depth-6 pipe ----
    {
        int Pb = wv * 36 + half;
        // prefetch all 36 base-pixel indices (LDS broadcast) into registers
        int pixv[36];
#pragma unroll
        for (int i = 0; i < 36; ++i) {
            int tl_ = (i >= 18);
            pixv[i] = s_pix[tl_][Pb + 2 * (i - 18 * tl_)];
        }
        unsigned buf[SLOTS][4];

#define ISSUE(gi)                                                                  \
        do {                                                                       \
            const __bf16* a0 = xn + (ptrdiff_t)pixv[(gi)] * C_ + 2 * li;           \
            const __bf16* a1 = a0 + W_ * C_;                                       \
            asm volatile("global_load_dword %0, %4, off\n\t"                       \
                         "global_load_dword %1, %4, off offset:128\n\t"            \
                         "global_load_dword %2, %5, off\n\t"                       \
                         "global_load_dword %3, %5, off offset:128"                \
                         : "=&v"(buf[(gi) % SLOTS][0]), "=&v"(buf[(gi) % SLOTS][1]),\
                           "=&v"(buf[(gi) % SLOTS][2]), "=&v"(buf[(gi) % SLOTS][3])\
                         : "v"(a0), "v"(a1));                                      \
        } while (0)

#define STEP(g, NW)                                                                \
        do {                                                                       \
            if ((g) + DEPTH < 36) ISSUE((g) + DEPTH);                              \
            int tl_ = ((g) >= 18);                                                 \
            int P_  = Pb + 2 * ((g) - 18 * tl_);                                   \
            floatx4 w4_ = s_w4[tl_][P_];                                           \
            asm volatile("s_waitcnt vmcnt(" #NW ")" ::: "memory");                 \
            __builtin_amdgcn_sched_barrier(0);                                     \
            float lo = w4_[0] * bflo(buf[(g) % SLOTS][0])                          \
                     + w4_[1] * bflo(buf[(g) % SLOTS][1])                          \
                     + w4_[2] * bflo(buf[(g) % SLOTS][2])                          \
                     + w4_[3] * bflo(buf[(g) % SLOTS][3]);                         \
            float hi = w4_[0] * bfhi(buf[(g) % SLOTS][0])                          \
                     + w4_[1] * bfhi(buf[(g) % SLOTS][1])                          \
                     + w4_[2] * bfhi(buf[(g) % SLOTS][2])                          \
                     + w4_[3] * bfhi(buf[(g) % SLOTS][3]);                         \
            floatx2 fv = {lo, hi};                                                 \
            bf16x2 bv = __builtin_convertvector(fv, bf16x2);                       \
            int k_ = P_ >> 4, p_ = P_ & 15;                                        \
            *(unsigned*)&s_x[tl_][p_ * SST + k_ * 64 + 2 * li] =                   \
                __builtin_bit_cast(unsigned, bv);                                  \
        } while (0)

        ISSUE(0); ISSUE(1); ISSUE(2); ISSUE(3); ISSUE(4); ISSUE(5);
        STEP(0, 24);  STEP(1, 24);  STEP(2, 24);  STEP(3, 24);  STEP(4, 24);
        STEP(5, 24);  STEP(6, 24);  STEP(7, 24);  STEP(8, 24);  STEP(9, 24);
        STEP(10, 24); STEP(11, 24); STEP(12, 24); STEP(13, 24); STEP(14, 24);
        STEP(15, 24); STEP(16, 24); STEP(17, 24); STEP(18, 24); STEP(19, 24);
        STEP(20, 24); STEP(21, 24); STEP(22, 24); STEP(23, 24); STEP(24, 24);
        STEP(25, 24); STEP(26, 24); STEP(27, 24); STEP(28, 24); STEP(29, 24);
        STEP(30, 20); STEP(31, 16); STEP(32, 12); STEP(33, 8);  STEP(34, 4);
        STEP(35, 0);
#undef STEP
#undef ISSUE
    }
    __syncthreads();

    // ---- Phase D: main conv MFMA, A-fragments shared across both tiles ----
    {
        const __bf16* ar = w2 + (size_t)(16 * wv + col) * CK + q * 8;
        const __bf16* b0 = s_x[0] + col * SST + q * 8;
        const __bf16* b1 = s_x[1] + col * SST + q * 8;
        floatx4 acc0 = {0.f, 0.f, 0.f, 0.f}, acc1 = {0.f, 0.f, 0.f, 0.f};
        bf16x8 a_cur = *(const bf16x8*)ar;
#pragma unroll
        for (int it = 0; it < 18; ++it) {
            bf16x8 a_nxt;
            if (it < 17) a_nxt = *(const bf16x8*)(ar + 32 * (it + 1));
            bf16x8 bb0 = *(const bf16x8*)(b0 + 32 * it);
            bf16x8 bb1 = *(const bf16x8*)(b1 + 32 * it);
            acc0 = __builtin_amdgcn_mfma_f32_16x16x32_bf16(a_cur, bb0, acc0, 0, 0, 0);
            acc1 = __builtin_amdgcn_mfma_f32_16x16x32_bf16(a_cur, bb1, acc1, 0, 0, 0);
            a_cur = a_nxt;
        }
#pragma unroll
        for (int r = 0; r < 4; ++r) {
            int o = 16 * wv + q * 4 + r;
            float bias = b[o];
            float* ob = out + (((size_t)n * COUT + o) * H_ + ho) * W_ + wo0;
            ob[col]      = fmaxf(acc0[r] + bias, 0.f);
            ob[16 + col] = fmaxf(acc1[r] + bias, 0.f);
        }
    }
}

extern "C" void kernel_launch(void* const* d_in, const int* in_sizes, int n_in,
                              void* d_out, int out_size, void* d_ws, size_t ws_size,
                              hipStream_t stream) {
    const float* x     = (const float*)d_in[0];
    const float* w_off = (const float*)d_in[1];
    const float* b_off = (const float*)d_in[2];
    const float* w     = (const float*)d_in[3];
    const float* b     = (const float*)d_in[4];
    float* out = (float*)d_out;

    // workspace: [256B guard][xT NHWC bf16 8.39MB][256B guard][w2][w_off2]
    __bf16* xT     = (__bf16*)d_ws + GUARD;
    __bf16* w2     = xT + (size_t)N_ * HW_ * C_ + GUARD;
    __bf16* w_off2 = w2 + (size_t)COUT * CK;

    prep_kernel<<<dim3(5, 128, 4), 256, 0, stream>>>(x, w, w_off, xT, w2, w_off2);

    int nblocks = N_ * H_ * W_ / (TP * NT);   // 2048
    fused_kernel<<<nblocks, 256, 0, stream>>>(xT, w2, w_off2, b_off, b, out);
}

// Round 10
// 120.937 us; speedup vs baseline: 1.1105x; 1.0120x over previous
//
#include <hip/hip_runtime.h>
#include <math.h>

#define N_ 4
#define C_ 64
#define H_ 128
#define W_ 128
#define HW_ (H_ * W_)
#define K2_ 9
#define COUT 64
#define CK 576          // K = 9 taps * 64 channels, order k*64+c
#define TP 16           // pixels per tile
#define NT 2            // tiles per block
#define SST 584         // s_x row stride (elems)
#define GUARD 128       // guard elems (256 B) before/after xT for unclamped-x loads
#define DEPTH 6         // gather pipeline: groups in flight
#define SLOTS 7         // buf slots (issue-before-consume needs DEPTH+1)

typedef __bf16 bf16x8 __attribute__((ext_vector_type(8)));
typedef __bf16 bf16x2 __attribute__((ext_vector_type(2)));
typedef float floatx4 __attribute__((ext_vector_type(4)));
typedef float floatx2 __attribute__((ext_vector_type(2)));
typedef unsigned uint2v __attribute__((ext_vector_type(2)));

__device__ __forceinline__ float bflo(unsigned u) {
    return __builtin_bit_cast(float, u << 16);
}
__device__ __forceinline__ float bfhi(unsigned u) {
    return __builtin_bit_cast(float, u & 0xffff0000u);
}

// ---- prep: (a) NCHW fp32 -> NHWC bf16 transpose, (b) weight re-layout ----
__global__ __launch_bounds__(256) void prep_kernel(const float* __restrict__ x,
                                                   const float* __restrict__ w,
                                                   const float* __restrict__ w_off,
                                                   __bf16* __restrict__ xT,
                                                   __bf16* __restrict__ w2,
                                                   __bf16* __restrict__ w_off2) {
    __shared__ float s_t[64][33];
    int t = threadIdx.x;
    int bx = blockIdx.x;
    int y = blockIdx.y, n = blockIdx.z;
    if (bx < 4) {
        int x0 = bx * 32;
        int c = t >> 2, seg = (t & 3) * 8;
        const float* src = x + (((size_t)n * C_ + c) * H_ + y) * W_ + x0 + seg;
        floatx4 v0 = *(const floatx4*)src;
        floatx4 v1 = *(const floatx4*)(src + 4);
#pragma unroll
        for (int j = 0; j < 4; ++j) { s_t[c][seg + j] = v0[j]; s_t[c][seg + 4 + j] = v1[j]; }
        __syncthreads();
        int xl = t >> 3, cb = (t & 7) * 8;
        bf16x8 o;
#pragma unroll
        for (int j = 0; j < 8; ++j) o[j] = (__bf16)s_t[cb + j][xl];
        *(bf16x8*)(xT + (((size_t)n * H_ + y) * W_ + x0 + xl) * C_ + cb) = o;
    } else {
        int linear = (n * 128 + y) * 256 + t;
        if (linear < COUT * CK) {
            int o = linear / CK, r = linear - o * CK;
            int k = r >> 6, c = r & 63;
            w2[linear] = (__bf16)w[(o * C_ + c) * K2_ + k];
        }
        if (linear < 32 * CK) {
            int o = linear / CK, r = linear - o * CK;
            int k = r >> 6, c = r & 63;
            w_off2[linear] = (o < 27) ? (__bf16)w_off[(o * C_ + c) * K2_ + k] : (__bf16)0.f;
        }
    }
}

// R4 base (= R0 structure + asm-pinned Phase-C gather pipeline, proven 49.7us and
// robust to consume-math edits) + two isolated micro-cuts:
//  - Phase C consume uses packed floatx2 accumulation -> v_pk_fma_f32
//    (3 instr/tap vs 4; -144 VALU instr/wave).
//  - s_setprio(1) around Phase B/D MFMA clusters (T5: blocks on a CU are
//    phase-diverse here, the regime where setprio measured positive).
__global__ __launch_bounds__(256) void fused_kernel(const __bf16* __restrict__ xT,
                                                    const __bf16* __restrict__ w2,
                                                    const __bf16* __restrict__ w_off2,
                                                    const float* __restrict__ b_off,
                                                    const float* __restrict__ b,
                                                    float* __restrict__ out) {
    __shared__ __align__(16) __bf16 s_x[NT][TP * SST];  // sampled B^T tiles [p][k*64+c]
    __shared__ float s_om[NT][2][32 * TP];              // offset-conv K-half partials
    __shared__ floatx4 s_w4[NT][K2_ * TP];              // position weights (mask folded)
    __shared__ int s_pix[NT][K2_ * TP];                 // clamped base pixel index

    int t = threadIdx.x;
    int pixbase = blockIdx.x * (TP * NT);               // over N*H*W, 32 px/block
    int wo0 = pixbase & (W_ - 1);                       // 0,32,64,96 (never crosses row)
    int ho  = (pixbase >> 7) & (H_ - 1);
    int n   = pixbase >> 14;
    const __bf16* xn = xT + (size_t)n * HW_ * C_;

    int lane = t & 63;
    int wv   = t >> 6;
    int half = lane >> 5;
    int li   = lane & 31;
    int q    = lane >> 4;
    int col  = lane & 15;

    // ---- Phase A: im2col, pixel-PAIR dwordx2 loads (18/wave, guarded unclamped-x) ----
    {
        uint2v ua[18];
        int tl = wv >> 1;                               // wave-uniform tile
        int rb = (wv & 1) * 36 + half;                  // pair index base within tile
#pragma unroll
        for (int j = 0; j < 18; ++j) {
            int r  = rb + 2 * j;                        // 0..71: k = r>>3, pj = r&7
            int k  = r >> 3;
            int p0 = (r & 7) * 2;
            int kh = k / 3, kw = k - kh * 3;
            int y  = ho - 1 + kh;
            int yc = min(max(y, 0), H_ - 1);
            int xx = wo0 + 16 * tl + p0 - 1 + kw;       // unclamped: -1..127 (pair: xx, xx+1)
            int pix = yc * W_ + xx;                     // guard makes -1/OOB reads safe
            ua[j] = *((const uint2v*)(xn + (ptrdiff_t)pix * C_) + li);
        }
#pragma unroll
        for (int j = 0; j < 18; ++j) {
            int r  = rb + 2 * j;
            int k  = r >> 3;
            int p0 = (r & 7) * 2;
            int kh = k / 3, kw = k - kh * 3;
            int y  = ho - 1 + kh;
            int xx = wo0 + 16 * tl + p0 - 1 + kw;
            bool vy = (unsigned)y < (unsigned)H_;
            // lanes 0..15 hold pixel p0 (tap xx), lanes 16..31 hold p0+1 (tap xx+1)
            int myxx = xx + (li >> 4);
            bool valid = vy && ((unsigned)myxx < (unsigned)W_);
            uint2v v = ua[j];
            v.x = valid ? v.x : 0u;
            v.y = valid ? v.y : 0u;
            int p = p0 + (li >> 4);
            *(uint2v*)&s_x[tl][p * SST + k * 64 + 4 * (li & 15)] = v;
        }
    }
    __syncthreads();

    // ---- Phase B: offset conv, 4 waves = (row-tile r, K-half h); B from LDS; A shared ----
    {
        int r = wv >> 1;
        int h = wv & 1;
        const __bf16* ar = w_off2 + (size_t)(16 * r + col) * CK + h * 288 + q * 8;
        const __bf16* b0 = s_x[0] + col * SST + h * 288 + q * 8;
        const __bf16* b1 = s_x[1] + col * SST + h * 288 + q * 8;
        floatx4 acc0 = {0.f, 0.f, 0.f, 0.f}, acc1 = {0.f, 0.f, 0.f, 0.f};
        __builtin_amdgcn_s_setprio(1);
#pragma unroll
        for (int it = 0; it < 9; ++it) {
            bf16x8 a   = *(const bf16x8*)(ar + 32 * it);
            bf16x8 bb0 = *(const bf16x8*)(b0 + 32 * it);
            bf16x8 bb1 = *(const bf16x8*)(b1 + 32 * it);
            acc0 = __builtin_amdgcn_mfma_f32_16x16x32_bf16(a, bb0, acc0, 0, 0, 0);
            acc1 = __builtin_amdgcn_mfma_f32_16x16x32_bf16(a, bb1, acc1, 0, 0, 0);
        }
        __builtin_amdgcn_s_setprio(0);
#pragma unroll
        for (int rr = 0; rr < 4; ++rr) {
            s_om[0][h][(16 * r + q * 4 + rr) * TP + col] = acc0[rr];
            s_om[1][h][(16 * r + q * 4 + rr) * TP + col] = acc1[rr];
        }
    }
    __syncthreads();

    // ---- coords: position-weights + clamped base pixel (288 items, 2 passes) ----
#pragma unroll
    for (int it2 = 0; it2 < 2; ++it2) {
        int i = it2 * 256 + t;
        if (i < NT * K2_ * TP) {
            int tl = (i >= 144);
            int P  = i - 144 * tl;
            int k  = P >> 4;
            int pp = P & 15;
            float dy = s_om[tl][0][(2 * k) * TP + pp]     + s_om[tl][1][(2 * k) * TP + pp]     + b_off[2 * k];
            float dx = s_om[tl][0][(2 * k + 1) * TP + pp] + s_om[tl][1][(2 * k + 1) * TP + pp] + b_off[2 * k + 1];
            float mm = s_om[tl][0][(18 + k) * TP + pp]    + s_om[tl][1][(18 + k) * TP + pp]    + b_off[18 + k];
            float msk = 1.f / (1.f + expf(-mm));
            int kh = k / 3, kw = k - kh * 3;
            float py = (float)(ho - 1 + kh) + dy;
            float px = (float)(wo0 + 16 * tl + pp - 1 + kw) + dx;
            float yf = floorf(py), xf = floorf(px);
            float fy = py - yf, fx = px - xf;
            int y0 = (int)yf, x0 = (int)xf;
            float wy0 = ((unsigned)y0 < (unsigned)H_)       ? 1.f - fy : 0.f;
            float wy1 = ((unsigned)(y0 + 1) < (unsigned)H_) ? fy       : 0.f;
            float wx0 = ((unsigned)x0 < (unsigned)W_)       ? 1.f - fx : 0.f;
            float wx1 = ((unsigned)(x0 + 1) < (unsigned)W_) ? fx      : 0.f;
            int y0c = min(max(y0, 0), H_ - 2);
            int x0c = min(max(x0, 0), W_ - 2);
            // shift weights onto clamped positions (OOB-safe addresses, exact zeros)
            float t0 = (y0 == y0c) ? wy0 : ((y0 + 1 == y0c) ? wy1 : 0.f);
            float t1 = (y0 == y0c) ? wy1 : ((y0 == y0c + 1) ? wy0 : 0.f);
            float u0 = (x0 == x0c) ? wx0 : ((x0 + 1 == x0c) ? wx1 : 0.f);
            float u1 = (x0 == x0c) ? wx1 : ((x0 == x0c + 1) ? wx0 : 0.f);
            floatx4 w4 = { t0 * u0 * msk, t0 * u1 * msk, t1 * u0 * msk, t1 * u1 * msk };
            s_w4[tl][P] = w4;
            s_pix[tl][P] = y0c * W_ + x0c;
        }
    }
    __syncthreads();

    // ---- Phase C: bilinear sample; half-wave per (k,p); 36 groups, asm depth-6 pipe ----
    {
        int Pb = wv * 36 + half;
        // prefetch all 36 base-pixel indices (LDS broadcast) into registers
        int pixv[36];
#pragma unroll
        for (int i = 0; i < 36; ++i) {
            int tl_ = (i >= 18);
            pixv[i] = s_pix[tl_][Pb + 2 * (i - 18 * tl_)];
        }
        unsigned buf[SLOTS][4];

        // issue 4 dword gathers for group gi into slot (gi % SLOTS); asm pins order
        // and register liveness (the allocator sank these loads in R1/R2/R3).
#define ISSUE(gi)                                                                  \
        do {                                                                       \
            const __bf16* a0 = xn + (ptrdiff_t)pixv[(gi)] * C_ + 2 * li;           \
            const __bf16* a1 = a0 + W_ * C_;                                       \
            asm volatile("global_load_dword %0, %4, off\n\t"                       \
                         "global_load_dword %1, %4, off offset:128\n\t"            \
                         "global_load_dword %2, %5, off\n\t"                       \
                         "global_load_dword %3, %5, off offset:128"                \
                         : "=&v"(buf[(gi) % SLOTS][0]), "=&v"(buf[(gi) % SLOTS][1]),\
                           "=&v"(buf[(gi) % SLOTS][2]), "=&v"(buf[(gi) % SLOTS][3])\
                         : "v"(a0), "v"(a1));                                      \
        } while (0)

        // step g: issue g+DEPTH, wait group g complete, consume with packed math.
#define STEP(g, NW)                                                                \
        do {                                                                       \
            if ((g) + DEPTH < 36) ISSUE((g) + DEPTH);                              \
            int tl_ = ((g) >= 18);                                                 \
            int P_  = Pb + 2 * ((g) - 18 * tl_);                                   \
            floatx4 w4_ = s_w4[tl_][P_];                                           \
            asm volatile("s_waitcnt vmcnt(" #NW ")" ::: "memory");                 \
            __builtin_amdgcn_sched_barrier(0);                                     \
            floatx2 sa = {0.f, 0.f};                                               \
            _Pragma("unroll")                                                      \
            for (int tp = 0; tp < 4; ++tp) {                                       \
                unsigned u_ = buf[(g) % SLOTS][tp];                                \
                floatx2 pa = {bflo(u_), bfhi(u_)};                                 \
                sa += pa * w4_[tp];                     /* v_pk_fma_f32 */         \
            }                                                                      \
            bf16x2 bv = __builtin_convertvector(sa, bf16x2);                       \
            int k_ = P_ >> 4, p_ = P_ & 15;                                        \
            *(unsigned*)&s_x[tl_][p_ * SST + k_ * 64 + 2 * li] =                   \
                __builtin_bit_cast(unsigned, bv);                                  \
        } while (0)

        ISSUE(0); ISSUE(1); ISSUE(2); ISSUE(3); ISSUE(4); ISSUE(5);
        STEP(0, 24);  STEP(1, 24);  STEP(2, 24);  STEP(3, 24);  STEP(4, 24);
        STEP(5, 24);  STEP(6, 24);  STEP(7, 24);  STEP(8, 24);  STEP(9, 24);
        STEP(10, 24); STEP(11, 24); STEP(12, 24); STEP(13, 24); STEP(14, 24);
        STEP(15, 24); STEP(16, 24); STEP(17, 24); STEP(18, 24); STEP(19, 24);
        STEP(20, 24); STEP(21, 24); STEP(22, 24); STEP(23, 24); STEP(24, 24);
        STEP(25, 24); STEP(26, 24); STEP(27, 24); STEP(28, 24); STEP(29, 24);
        STEP(30, 20); STEP(31, 16); STEP(32, 12); STEP(33, 8);  STEP(34, 4);
        STEP(35, 0);
#undef STEP
#undef ISSUE
    }
    __syncthreads();

    // ---- Phase D: main conv MFMA, A-fragments shared across both tiles ----
    {
        const __bf16* ar = w2 + (size_t)(16 * wv + col) * CK + q * 8;
        const __bf16* b0 = s_x[0] + col * SST + q * 8;
        const __bf16* b1 = s_x[1] + col * SST + q * 8;
        floatx4 acc0 = {0.f, 0.f, 0.f, 0.f}, acc1 = {0.f, 0.f, 0.f, 0.f};
        bf16x8 a_cur = *(const bf16x8*)ar;
        __builtin_amdgcn_s_setprio(1);
#pragma unroll
        for (int it = 0; it < 18; ++it) {
            bf16x8 a_nxt;
            if (it < 17) a_nxt = *(const bf16x8*)(ar + 32 * (it + 1));
            bf16x8 bb0 = *(const bf16x8*)(b0 + 32 * it);
            bf16x8 bb1 = *(const bf16x8*)(b1 + 32 * it);
            acc0 = __builtin_amdgcn_mfma_f32_16x16x32_bf16(a_cur, bb0, acc0, 0, 0, 0);
            acc1 = __builtin_amdgcn_mfma_f32_16x16x32_bf16(a_cur, bb1, acc1, 0, 0, 0);
            a_cur = a_nxt;
        }
        __builtin_amdgcn_s_setprio(0);
#pragma unroll
        for (int r = 0; r < 4; ++r) {
            int o = 16 * wv + q * 4 + r;
            float bias = b[o];
            float* ob = out + (((size_t)n * COUT + o) * H_ + ho) * W_ + wo0;
            ob[col]      = fmaxf(acc0[r] + bias, 0.f);
            ob[16 + col] = fmaxf(acc1[r] + bias, 0.f);
        }
    }
}

extern "C" void kernel_launch(void* const* d_in, const int* in_sizes, int n_in,
                              void* d_out, int out_size, void* d_ws, size_t ws_size,
                              hipStream_t stream) {
    const float* x     = (const float*)d_in[0];
    const float* w_off = (const float*)d_in[1];
    const float* b_off = (const float*)d_in[2];
    const float* w     = (const float*)d_in[3];
    const float* b     = (const float*)d_in[4];
    float* out = (float*)d_out;

    // workspace: [256B guard][xT NHWC bf16 8.39MB][256B guard][w2][w_off2]
    __bf16* xT     = (__bf16*)d_ws + GUARD;
    __bf16* w2     = xT + (size_t)N_ * HW_ * C_ + GUARD;
    __bf16* w_off2 = w2 + (size_t)COUT * CK;

    prep_kernel<<<dim3(5, 128, 4), 256, 0, stream>>>(x, w, w_off, xT, w2, w_off2);

    int nblocks = N_ * H_ * W_ / (TP * NT);   // 2048
    fused_kernel<<<nblocks, 256, 0, stream>>>(xT, w2, w_off2, b_off, b, out);
}

// Round 11
// 120.284 us; speedup vs baseline: 1.1165x; 1.0054x over previous
//
#include <hip/hip_runtime.h>
#include <math.h>

#define N_ 4
#define C_ 64
#define H_ 128
#define W_ 128
#define HW_ (H_ * W_)
#define K2_ 9
#define COUT 64
#define CK 576          // K = 9 taps * 64 channels, order k*64+c
#define TP 16           // pixels per tile
#define NT 2            // tiles per block
#define SST 584         // s_x row stride (elems)
#define GUARD 128       // guard elems (256 B) before/after xT for unclamped-x loads
#define DEPTH 6         // gather pipeline: groups in flight
#define SLOTS 7         // buf slots (issue-before-consume needs DEPTH+1)

typedef __bf16 bf16x8 __attribute__((ext_vector_type(8)));
typedef __bf16 bf16x2 __attribute__((ext_vector_type(2)));
typedef float floatx4 __attribute__((ext_vector_type(4)));
typedef float floatx2 __attribute__((ext_vector_type(2)));
typedef unsigned uint2v __attribute__((ext_vector_type(2)));
typedef unsigned uint4v __attribute__((ext_vector_type(4)));

__device__ __forceinline__ float bflo(unsigned u) {
    return __builtin_bit_cast(float, u << 16);
}
__device__ __forceinline__ float bfhi(unsigned u) {
    return __builtin_bit_cast(float, u & 0xffff0000u);
}

// ---- prep v2: 4 rows/block (8 asm-pinned dwordx4 loads/thread = 4x MLP of v1),
// grid 2560 -> 640 blocks; weight re-layout compressed 512 -> 128 blocks.
// The bench metric includes prep (+~70us constant vs fused across R0-R10); prep v1
// was 2 loads/thread over 2560 light blocks -- the same shallow-MLP latency
// profile diagnosed in the fused kernel all session.
__global__ __launch_bounds__(256) void prep_kernel(const float* __restrict__ x,
                                                   const float* __restrict__ w,
                                                   const float* __restrict__ w_off,
                                                   __bf16* __restrict__ xT,
                                                   __bf16* __restrict__ w2,
                                                   __bf16* __restrict__ w_off2) {
    __shared__ float s_t[4][64][33];
    int t = threadIdx.x;
    int bx = blockIdx.x;
    int yq = blockIdx.y, n = blockIdx.z;
    if (bx < 4) {
        int x0 = bx * 32;
        int y0 = yq * 4;
        int c = t >> 2, seg = (t & 3) * 8;
        const float* src0 = x + (((size_t)n * C_ + c) * H_ + y0) * W_ + x0 + seg;
        uint4v va[8];
#pragma unroll
        for (int r = 0; r < 4; ++r) {
            asm volatile("global_load_dwordx4 %0, %1, off"
                         : "=&v"(va[2 * r]) : "v"(src0 + r * W_));
            asm volatile("global_load_dwordx4 %0, %1, off"
                         : "=&v"(va[2 * r + 1]) : "v"(src0 + r * W_ + 4));
        }
        asm volatile("s_waitcnt vmcnt(0)" ::: "memory");
        __builtin_amdgcn_sched_barrier(0);
#pragma unroll
        for (int r = 0; r < 4; ++r) {
            floatx4 v0 = __builtin_bit_cast(floatx4, va[2 * r]);
            floatx4 v1 = __builtin_bit_cast(floatx4, va[2 * r + 1]);
#pragma unroll
            for (int j = 0; j < 4; ++j) {
                s_t[r][c][seg + j]     = v0[j];
                s_t[r][c][seg + 4 + j] = v1[j];
            }
        }
        __syncthreads();
        int xl = t >> 3, cb = (t & 7) * 8;
#pragma unroll
        for (int r = 0; r < 4; ++r) {
            bf16x8 o;
#pragma unroll
            for (int j = 0; j < 8; ++j) o[j] = (__bf16)s_t[r][cb + j][xl];
            *(bf16x8*)(xT + (((size_t)n * H_ + y0 + r) * W_ + x0 + xl) * C_ + cb) = o;
        }
    } else {
        // weights: 128 blocks (yq 0..31, n 0..3) x 256 thr x 2 elems = 65536 slots
        int base = ((n * 32 + yq) * 256 + t) * 2;
#pragma unroll
        for (int e = 0; e < 2; ++e) {
            int linear = base + e;
            if (linear < COUT * CK) {
                int o = linear / CK, r = linear - o * CK;
                int k = r >> 6, c = r & 63;
                w2[linear] = (__bf16)w[(o * C_ + c) * K2_ + k];
            }
            if (linear < 32 * CK) {
                int o = linear / CK, r = linear - o * CK;
                int k = r >> 6, c = r & 63;
                w_off2[linear] = (o < 27) ? (__bf16)w_off[(o * C_ + c) * K2_ + k] : (__bf16)0.f;
            }
        }
    }
}

// fused: exact R4 source (proven 49.7us; NT=2, asm-pinned depth-6 gather).
// R10's pk-math and setprio reverted (both measured slightly negative).
__global__ __launch_bounds__(256) void fused_kernel(const __bf16* __restrict__ xT,
                                                    const __bf16* __restrict__ w2,
                                                    const __bf16* __restrict__ w_off2,
                                                    const float* __restrict__ b_off,
                                                    const float* __restrict__ b,
                                                    float* __restrict__ out) {
    __shared__ __align__(16) __bf16 s_x[NT][TP * SST];  // sampled B^T tiles [p][k*64+c]
    __shared__ float s_om[NT][2][32 * TP];              // offset-conv K-half partials
    __shared__ floatx4 s_w4[NT][K2_ * TP];              // position weights (mask folded)
    __shared__ int s_pix[NT][K2_ * TP];                 // clamped base pixel index

    int t = threadIdx.x;
    int pixbase = blockIdx.x * (TP * NT);               // over N*H*W, 32 px/block
    int wo0 = pixbase & (W_ - 1);                       // 0,32,64,96 (never crosses row)
    int ho  = (pixbase >> 7) & (H_ - 1);
    int n   = pixbase >> 14;
    const __bf16* xn = xT + (size_t)n * HW_ * C_;

    int lane = t & 63;
    int wv   = t >> 6;
    int half = lane >> 5;
    int li   = lane & 31;
    int q    = lane >> 4;
    int col  = lane & 15;

    // ---- Phase A: im2col, pixel-PAIR dwordx2 loads (18/wave, guarded unclamped-x) ----
    {
        uint2v ua[18];
        int tl = wv >> 1;                               // wave-uniform tile
        int rb = (wv & 1) * 36 + half;                  // pair index base within tile
#pragma unroll
        for (int j = 0; j < 18; ++j) {
            int r  = rb + 2 * j;                        // 0..71: k = r>>3, pj = r&7
            int k  = r >> 3;
            int p0 = (r & 7) * 2;
            int kh = k / 3, kw = k - kh * 3;
            int y  = ho - 1 + kh;
            int yc = min(max(y, 0), H_ - 1);
            int xx = wo0 + 16 * tl + p0 - 1 + kw;       // unclamped: -1..127 (pair: xx, xx+1)
            int pix = yc * W_ + xx;                     // guard makes -1/OOB reads safe
            ua[j] = *((const uint2v*)(xn + (ptrdiff_t)pix * C_) + li);
        }
#pragma unroll
        for (int j = 0; j < 18; ++j) {
            int r  = rb + 2 * j;
            int k  = r >> 3;
            int p0 = (r & 7) * 2;
            int kh = k / 3, kw = k - kh * 3;
            int y  = ho - 1 + kh;
            int xx = wo0 + 16 * tl + p0 - 1 + kw;
            bool vy = (unsigned)y < (unsigned)H_;
            // lanes 0..15 hold pixel p0 (tap xx), lanes 16..31 hold p0+1 (tap xx+1)
            int myxx = xx + (li >> 4);
            bool valid = vy && ((unsigned)myxx < (unsigned)W_);
            uint2v v = ua[j];
            v.x = valid ? v.x : 0u;
            v.y = valid ? v.y : 0u;
            int p = p0 + (li >> 4);
            *(uint2v*)&s_x[tl][p * SST + k * 64 + 4 * (li & 15)] = v;
        }
    }
    __syncthreads();

    // ---- Phase B: offset conv, 4 waves = (row-tile r, K-half h); B from LDS; A shared ----
    {
        int r = wv >> 1;
        int h = wv & 1;
        const __bf16* ar = w_off2 + (size_t)(16 * r + col) * CK + h * 288 + q * 8;
        const __bf16* b0 = s_x[0] + col * SST + h * 288 + q * 8;
        const __bf16* b1 = s_x[1] + col * SST + h * 288 + q * 8;
        floatx4 acc0 = {0.f, 0.f, 0.f, 0.f}, acc1 = {0.f, 0.f, 0.f, 0.f};
#pragma unroll
        for (int it = 0; it < 9; ++it) {
            bf16x8 a   = *(const bf16x8*)(ar + 32 * it);
            bf16x8 bb0 = *(const bf16x8*)(b0 + 32 * it);
            bf16x8 bb1 = *(const bf16x8*)(b1 + 32 * it);
            acc0 = __builtin_amdgcn_mfma_f32_16x16x32_bf16(a, bb0, acc0, 0, 0, 0);
            acc1 = __builtin_amdgcn_mfma_f32_16x16x32_bf16(a, bb1, acc1, 0, 0, 0);
        }
#pragma unroll
        for (int rr = 0; rr < 4; ++rr) {
            s_om[0][h][(16 * r + q * 4 + rr) * TP + col] = acc0[rr];
            s_om[1][h][(16 * r + q * 4 + rr) * TP + col] = acc1[rr];
        }
    }
    __syncthreads();

    // ---- coords: position-weights + clamped base pixel (288 items, 2 passes) ----
#pragma unroll
    for (int it2 = 0; it2 < 2; ++it2) {
        int i = it2 * 256 + t;
        if (i < NT * K2_ * TP) {
            int tl = (i >= 144);
            int P  = i - 144 * tl;
            int k  = P >> 4;
            int pp = P & 15;
            float dy = s_om[tl][0][(2 * k) * TP + pp]     + s_om[tl][1][(2 * k) * TP + pp]     + b_off[2 * k];
            float dx = s_om[tl][0][(2 * k + 1) * TP + pp] + s_om[tl][1][(2 * k + 1) * TP + pp] + b_off[2 * k + 1];
            float mm = s_om[tl][0][(18 + k) * TP + pp]    + s_om[tl][1][(18 + k) * TP + pp]    + b_off[18 + k];
            float msk = 1.f / (1.f + expf(-mm));
            int kh = k / 3, kw = k - kh * 3;
            float py = (float)(ho - 1 + kh) + dy;
            float px = (float)(wo0 + 16 * tl + pp - 1 + kw) + dx;
            float yf = floorf(py), xf = floorf(px);
            float fy = py - yf, fx = px - xf;
            int y0 = (int)yf, x0 = (int)xf;
            float wy0 = ((unsigned)y0 < (unsigned)H_)       ? 1.f - fy : 0.f;
            float wy1 = ((unsigned)(y0 + 1) < (unsigned)H_) ? fy       : 0.f;
            float wx0 = ((unsigned)x0 < (unsigned)W_)       ? 1.f - fx : 0.f;
            float wx1 = ((unsigned)(x0 + 1) < (unsigned)W_) ? fx      : 0.f;
            int y0c = min(max(y0, 0), H_ - 2);
            int x0c = min(max(x0, 0), W_ - 2);
            // shift weights onto clamped positions (OOB-safe addresses, exact zeros)
            float t0 = (y0 == y0c) ? wy0 : ((y0 + 1 == y0c) ? wy1 : 0.f);
            float t1 = (y0 == y0c) ? wy1 : ((y0 == y0c + 1) ? wy0 : 0.f);
            float u0 = (x0 == x0c) ? wx0 : ((x0 + 1 == x0c) ? wx1 : 0.f);
            float u1 = (x0 == x0c) ? wx1 : ((x0 == x0c + 1) ? wx0 : 0.f);
            floatx4 w4 = { t0 * u0 * msk, t0 * u1 * msk, t1 * u0 * msk, t1 * u1 * msk };
            s_w4[tl][P] = w4;
            s_pix[tl][P] = y0c * W_ + x0c;
        }
    }
    __syncthreads();

    // ---- Phase C: bilinear sample; half-wave per (k,p); 36 groups, asm depth-6 pipe ----
    {
        int Pb = wv * 36 + half;
        // prefetch all 36 base-pixel indices (LDS broadcast) into registers
        int pixv[36];
#pragma unroll
        for (int i = 0; i < 36; ++i) {
            int tl_ = (i >= 18);
            pixv[i] = s_pix[tl_][Pb + 2 * (i - 18 * tl_)];
        }
        unsigned buf[SLOTS][4];

#define ISSUE(gi)                                                                  \
        do {                                                                       \
            const __bf16* a0 = xn + (ptrdiff_t)pixv[(gi)] * C_ + 2 * li;           \
            const __bf16* a1 = a0 + W_ * C_;                                       \
            asm volatile("global_load_dword %0, %4, off\n\t"                       \
                         "global_load_dword %1, %4, off offset:128\n\t"            \
                         "global_load_dword %2, %5, off\n\t"                       \
                         "global_load_dword %3, %5, off offset:128"                \
                         : "=&v"(buf[(gi) % SLOTS][0]), "=&v"(buf[(gi) % SLOTS][1]),\
                           "=&v"(buf[(gi) % SLOTS][2]), "=&v"(buf[(gi) % SLOTS][3])\
                         : "v"(a0), "v"(a1));                                      \
        } while (0)

#define STEP(g, NW)                                                                \
        do {                                                                       \
            if ((g) + DEPTH < 36) ISSUE((g) + DEPTH);                              \
            int tl_ = ((g) >= 18);                                                 \
            int P_  = Pb + 2 * ((g) - 18 * tl_);                                   \
            floatx4 w4_ = s_w4[tl_][P_];                                           \
            asm volatile("s_waitcnt vmcnt(" #NW ")" ::: "memory");                 \
            __builtin_amdgcn_sched_barrier(0);                                     \
            float lo = w4_[0] * bflo(buf[(g) % SLOTS][0])                          \
                     + w4_[1] * bflo(buf[(g) % SLOTS][1])                          \
                     + w4_[2] * bflo(buf[(g) % SLOTS][2])                          \
                     + w4_[3] * bflo(buf[(g) % SLOTS][3]);                         \
            float hi = w4_[0] * bfhi(buf[(g) % SLOTS][0])                          \
                     + w4_[1] * bfhi(buf[(g) % SLOTS][1])                          \
                     + w4_[2] * bfhi(buf[(g) % SLOTS][2])                          \
                     + w4_[3] * bfhi(buf[(g) % SLOTS][3]);                         \
            floatx2 fv = {lo, hi};                                                 \
            bf16x2 bv = __builtin_convertvector(fv, bf16x2);                       \
            int k_ = P_ >> 4, p_ = P_ & 15;                                        \
            *(unsigned*)&s_x[tl_][p_ * SST + k_ * 64 + 2 * li] =                   \
                __builtin_bit_cast(unsigned, bv);                                  \
        } while (0)

        ISSUE(0); ISSUE(1); ISSUE(2); ISSUE(3); ISSUE(4); ISSUE(5);
        STEP(0, 24);  STEP(1, 24);  STEP(2, 24);  STEP(3, 24);  STEP(4, 24);
        STEP(5, 24);  STEP(6, 24);  STEP(7, 24);  STEP(8, 24);  STEP(9, 24);
        STEP(10, 24); STEP(11, 24); STEP(12, 24); STEP(13, 24); STEP(14, 24);
        STEP(15, 24); STEP(16, 24); STEP(17, 24); STEP(18, 24); STEP(19, 24);
        STEP(20, 24); STEP(21, 24); STEP(22, 24); STEP(23, 24); STEP(24, 24);
        STEP(25, 24); STEP(26, 24); STEP(27, 24); STEP(28, 24); STEP(29, 24);
        STEP(30, 20); STEP(31, 16); STEP(32, 12); STEP(33, 8);  STEP(34, 4);
        STEP(35, 0);
#undef STEP
#undef ISSUE
    }
    __syncthreads();

    // ---- Phase D: main conv MFMA, A-fragments shared across both tiles ----
    {
        const __bf16* ar = w2 + (size_t)(16 * wv + col) * CK + q * 8;
        const __bf16* b0 = s_x[0] + col * SST + q * 8;
        const __bf16* b1 = s_x[1] + col * SST + q * 8;
        floatx4 acc0 = {0.f, 0.f, 0.f, 0.f}, acc1 = {0.f, 0.f, 0.f, 0.f};
        bf16x8 a_cur = *(const bf16x8*)ar;
#pragma unroll
        for (int it = 0; it < 18; ++it) {
            bf16x8 a_nxt;
            if (it < 17) a_nxt = *(const bf16x8*)(ar + 32 * (it + 1));
            bf16x8 bb0 = *(const bf16x8*)(b0 + 32 * it);
            bf16x8 bb1 = *(const bf16x8*)(b1 + 32 * it);
            acc0 = __builtin_amdgcn_mfma_f32_16x16x32_bf16(a_cur, bb0, acc0, 0, 0, 0);
            acc1 = __builtin_amdgcn_mfma_f32_16x16x32_bf16(a_cur, bb1, acc1, 0, 0, 0);
            a_cur = a_nxt;
        }
#pragma unroll
        for (int r = 0; r < 4; ++r) {
            int o = 16 * wv + q * 4 + r;
            float bias = b[o];
            float* ob = out + (((size_t)n * COUT + o) * H_ + ho) * W_ + wo0;
            ob[col]      = fmaxf(acc0[r] + bias, 0.f);
            ob[16 + col] = fmaxf(acc1[r] + bias, 0.f);
        }
    }
}

extern "C" void kernel_launch(void* const* d_in, const int* in_sizes, int n_in,
                              void* d_out, int out_size, void* d_ws, size_t ws_size,
                              hipStream_t stream) {
    const float* x     = (const float*)d_in[0];
    const float* w_off = (const float*)d_in[1];
    const float* b_off = (const float*)d_in[2];
    const float* w     = (const float*)d_in[3];
    const float* b     = (const float*)d_in[4];
    float* out = (float*)d_out;

    // workspace: [256B guard][xT NHWC bf16 8.39MB][256B guard][w2][w_off2]
    __bf16* xT     = (__bf16*)d_ws + GUARD;
    __bf16* w2     = xT + (size_t)N_ * HW_ * C_ + GUARD;
    __bf16* w_off2 = w2 + (size_t)COUT * CK;

    prep_kernel<<<dim3(5, 32, 4), 256, 0, stream>>>(x, w, w_off, xT, w2, w_off2);

    int nblocks = N_ * H_ * W_ / (TP * NT);   // 2048
    fused_kernel<<<nblocks, 256, 0, stream>>>(xT, w2, w_off2, b_off, b, out);
}